// Round 21
// baseline (363.674 us; speedup 1.0000x reference)
//
#include <hip/hip_runtime.h>
#include <hip/hip_fp16.h>

typedef __attribute__((ext_vector_type(8))) _Float16 half8;
typedef __attribute__((ext_vector_type(4))) _Float16 half4;
typedef __attribute__((ext_vector_type(4))) float float4a;

// ---- workspace layout (elements of _Float16) ----
#define WT_PLANE 3145728
#define WS_FC    6291456
#define WS_FC_LO 6307840
#define WS_Q     6324224          // per-block Q planes: [bl][Qh 16384 | Ql 16384]
#define Q_STRIDE 32768

// ---- LDS layout (bytes), total 163840 ----
#define OFF_KH   0
#define OFF_KL   32768
#define OFF_VST  65536
#define OFF_XB1  98304
#define OFF_PT   114688
#define OFF_PVH  147456
#define OFF_RED1 98304    // dead X region during phase B (no PVH alias)
#define OFF_RED2 99328
#define LDS_BYTES 163840

__device__ __forceinline__ int swz128(int r, int c) {
    return (r << 7) + ((((c >> 3) ^ r) & 7) << 4) + ((c & 7) << 1);
}
__device__ __forceinline__ int swz512(int r, int c) {
    return (r << 9) + (((((c >> 3) ^ (r & 7))) & 31) << 4) + ((c & 7) << 1);
}

// LDS-only barrier: does NOT drain vmcnt (global loads/stores stay in flight).
__device__ __forceinline__ void lds_barrier() {
    __builtin_amdgcn_sched_barrier(0);
    asm volatile("s_waitcnt lgkmcnt(0)" ::: "memory");
    __builtin_amdgcn_s_barrier();
    __builtin_amdgcn_sched_barrier(0);
}

// ---------------- prep: W -> WT (f16 hi/lo, transposed), fcw -> f16 hi/lo ----
extern "C" __global__ void __launch_bounds__(256)
va_prep(const float* __restrict__ Wq, const float* __restrict__ Wk,
        const float* __restrict__ Wv, const float* __restrict__ fcw,
        _Float16* __restrict__ ws)
{
    __shared__ float tile[16384];
    const int t = (int)threadIdx.x;
    const int blk = (int)blockIdx.x;
    if (blk < 192) {
        const int mat = blk >> 6, l = blk & 63;
        const float* W = (mat == 0 ? Wq : mat == 1 ? Wk : Wv) + l * 16384;
        #pragma unroll
        for (int i = 0; i < 16; ++i) {
            const int f = (i * 256 + t) * 4;
            *(float4a*)&tile[f] = *(const float4a*)(W + f);
        }
        __syncthreads();
        const int a = t & 63, cgp = t >> 6;
        const int obase = ((mat * 64 + l) * 64 + a) * 256;
        #pragma unroll
        for (int p = 0; p < 8; ++p) {
            const int c0 = cgp * 64 + p * 8;
            half8 hh, hl;
            #pragma unroll
            for (int q = 0; q < 8; ++q) {
                const float v = tile[(c0 + q) * 64 + a];
                const _Float16 h = (_Float16)v;
                hh[q] = h;
                hl[q] = (_Float16)(v - (float)h);
            }
            *(half8*)(ws + obase + c0) = hh;
            *(half8*)(ws + WT_PLANE + obase + c0) = hl;
        }
    } else {
        #pragma unroll
        for (int i = 0; i < 16; ++i) {
            const int f = (i * 256 + t) * 4;
            const float4a v = *(const float4a*)(fcw + f);
            half4 hh, hl;
            #pragma unroll
            for (int q = 0; q < 4; ++q) {
                const _Float16 h = (_Float16)v[q];
                hh[q] = h;
                hl[q] = (_Float16)(v[q] - (float)h);
            }
            *(half4*)(ws + WS_FC + f) = hh;
            *(half4*)(ws + WS_FC_LO + f) = hl;
        }
    }
}

// ---------------- main fused kernel ----------------
// r21: r20 (298us) + T5 s_setprio(1) around the MFMA-dense clusters
// (phase-A acompute, PV, fc+S-overlap). The schedule now has per-phase
// wave role diversity (S-overlap in the fc slot; xstage/wload vs MFMA in
// phase A), which is T5's prerequisite -- the CU scheduler can prefer
// MFMA-issuing waves while co-resident waves issue memory ops.
extern "C" __global__ void
__launch_bounds__(512)
__attribute__((amdgpu_waves_per_eu(2, 2)))
va_fused(const float* __restrict__ Y,
         const float* __restrict__ bq, const float* __restrict__ bk,
         const float* __restrict__ bv,
         const float* __restrict__ gama, const float* __restrict__ fcb,
         _Float16* __restrict__ ws,
         float* __restrict__ out)
{
    extern __shared__ char smem[];
    const int tid  = (int)threadIdx.x;
    const int w    = tid >> 6;    // wave 0..7
    const int lane = tid & 63;
    const int l15  = lane & 15;
    const int kg   = lane >> 4;

    // XCD-aware swizzle (bijective): each XCD sees a stable set of 8 l's.
    const int i0 = (int)blockIdx.x;
    const int x  = i0 & 7, q0 = i0 >> 3;
    const int b  = q0 >> 3;
    const int l  = ((q0 & 7) << 3) | x;

    const size_t base = (size_t)b * (256u * 16384u) + (size_t)l * 256u;
    const float* __restrict__ Yb = Y + base;
    float* __restrict__ Ob = out + base;
    const size_t qslot = (size_t)WS_Q + (size_t)((b << 6) | l) * Q_STRIDE;

    const int rg = w >> 2;   // phase A: row-group (rows rg*128..+127)
    const int cg = w & 3;    // phase A: a-subgroup

    // ============ Phase A: QKV = X * W (dbuf X, split-f16 MFMA) ============
    float4a acc[8][3];
    #pragma unroll
    for (int rt = 0; rt < 8; ++rt)
        #pragma unroll
        for (int ct = 0; ct < 3; ++ct) acc[rt][ct] = (float4a)0.0f;

    const int srow = tid >> 1;          // 0..255
    const int scol = (tid & 1) * 32;
    const float* xsrc = Yb + (size_t)srow * 16384 + scol;

    auto xstage = [&](const float4a* xr, int bufbase) {
        #pragma unroll
        for (int p = 0; p < 8; ++p) {
            const int c = scol + p * 4;
            half4 hh, hl;
            #pragma unroll
            for (int q = 0; q < 4; ++q) {
                const float v = xr[p][q];
                const _Float16 h = (_Float16)v;
                hh[q] = h;
                hl[q] = (_Float16)(v - (float)h);
            }
            *(half4*)(smem + bufbase + swz128(srow, c)) = hh;
            *(half4*)(smem + bufbase + 32768 + swz128(srow, c)) = hl;
        }
    };
    auto wload = [&](int kt, int ks, half8* bh, half8* bl) {
        #pragma unroll
        for (int ct = 0; ct < 3; ++ct) {
            const int widx = ((ct * 64 + l) * 64 + cg * 16 + l15) * 256
                             + kt * 64 + ks * 32 + kg * 8;
            bh[ct] = *(const half8*)(ws + widx);
            if (ct < 2) bl[ct] = *(const half8*)(ws + WT_PLANE + widx);
        }
    };
    auto acompute = [&](int bufbase, int coff, const half8* bh, const half8* bl) {
        __builtin_amdgcn_s_setprio(1);
        #pragma unroll
        for (int rt = 0; rt < 8; ++rt) {
            const int row = rg * 128 + rt * 16 + l15;
            const half8 ah = *(const half8*)(smem + bufbase + swz128(row, coff + kg * 8));
            const half8 al = *(const half8*)(smem + bufbase + 32768 + swz128(row, coff + kg * 8));
            #pragma unroll
            for (int ct = 0; ct < 2; ++ct) {
                acc[rt][ct] = __builtin_amdgcn_mfma_f32_16x16x32_f16(ah, bh[ct], acc[rt][ct], 0, 0, 0);
                acc[rt][ct] = __builtin_amdgcn_mfma_f32_16x16x32_f16(ah, bl[ct], acc[rt][ct], 0, 0, 0);
                acc[rt][ct] = __builtin_amdgcn_mfma_f32_16x16x32_f16(al, bh[ct], acc[rt][ct], 0, 0, 0);
            }
            // V: single term (Xh*Wvh); dropped Xl*Wvh ~8e-3, at f16-rounding scale.
            acc[rt][2] = __builtin_amdgcn_mfma_f32_16x16x32_f16(ah, bh[2], acc[rt][2], 0, 0, 0);
        }
        __builtin_amdgcn_s_setprio(0);
    };

    {
        float4a xr[8];
        #pragma unroll
        for (int p = 0; p < 8; ++p) xr[p] = *(const float4a*)(xsrc + p * 4);
        xstage(xr, 0);
        lds_barrier();
        #pragma unroll
        for (int p = 0; p < 8; ++p) xr[p] = *(const float4a*)(xsrc + 64 + p * 4);

        #pragma unroll 2
        for (int kt = 0; kt < 4; ++kt) {
            const int cur = (kt & 1) ? OFF_XB1 : 0;
            const int nxt = (kt & 1) ? 0 : OFF_XB1;
            if (kt < 3) xstage(xr, nxt);
            half8 bh0[3], bl0[2];
            wload(kt, 0, bh0, bl0);
            acompute(cur, 0, bh0, bl0);
            if (kt < 2) {
                #pragma unroll
                for (int p = 0; p < 8; ++p)
                    xr[p] = *(const float4a*)(xsrc + (kt + 2) * 64 + p * 4);
            }
            half8 bh1[3], bl1[2];
            wload(kt, 1, bh1, bl1);
            acompute(cur, 32, bh1, bl1);
            lds_barrier();
        }
    }

    // ---- epilogue: bias; K hi/lo + V^T -> LDS; Q -> linear staging @buf1 ----
    {
        const int a = cg * 16 + l15;
        const float biq = bq[a], bik = bk[a], biv = bv[a];
        #pragma unroll
        for (int rt = 0; rt < 8; ++rt) {
            #pragma unroll
            for (int jj = 0; jj < 4; ++jj) {
                const int m = rg * 128 + rt * 16 + kg * 4 + jj;
                const float qv = acc[rt][0][jj] + biq;
                const _Float16 qh_ = (_Float16)qv;
                *(_Float16*)(smem + OFF_XB1 + m * 128 + a * 2) = qh_;
                *(_Float16*)(smem + OFF_XB1 + 32768 + m * 128 + a * 2) =
                    (_Float16)(qv - (float)qh_);
                const float kv = acc[rt][1][jj] + bik;
                const _Float16 kh = (_Float16)kv;
                *(_Float16*)(smem + OFF_KH + swz128(m, a)) = kh;
                *(_Float16*)(smem + OFF_KL + swz128(m, a)) = (_Float16)(kv - (float)kh);
            }
            const int m0 = rg * 128 + rt * 16 + kg * 4;
            half4 vh;
            #pragma unroll
            for (int jj = 0; jj < 4; ++jj)
                vh[jj] = (_Float16)(acc[rt][2][jj] + biv);
            *(half4*)(smem + OFF_VST + swz512(a, m0)) = vh;
        }
    }
    lds_barrier();
    // coalesced Q export: LDS -> ws plane (half8 stores)
    {
        _Float16* pQhw = ws + qslot;
        _Float16* pQlw = pQhw + 16384;
        #pragma unroll
        for (int p = 0; p < 4; ++p) {
            const int e = tid * 32 + p * 8;
            *(half8*)(pQhw + e) = *(const half8*)(smem + OFF_XB1 + e * 2);
            *(half8*)(pQlw + e) = *(const half8*)(smem + OFF_XB1 + 32768 + e * 2);
        }
    }
    __syncthreads();   // full drain: Q stores visible (L2) to all waves' loads

    // ---- phase B constants ----
    const int rt_s = w & 3;    // chunk-local row-tile
    const int mq   = w >> 2;   // S: m-half
    const int ah2  = w >> 2;   // PV: a-half
    const int cgf  = w >> 2;   // fc: col-half (cc cgf*128..+127)
    const float gv = gama[0];
    float fcbv[8];
    #pragma unroll
    for (int i = 0; i < 8; ++i) fcbv[i] = fcb[cgf * 128 + i * 16 + l15];
    float* red1 = (float*)(smem + OFF_RED1);
    float* red2 = (float*)(smem + OFF_RED2);
    const _Float16* __restrict__ pQh = ws + qslot;
    const _Float16* __restrict__ pQl = pQh + 16384;

    half8 qfh[2], qfl[2];      // prefetched Q fragments for the chunk in flight
    auto loadQ = [&](int ci) {
        const int arow = ci * 64 + rt_s * 16 + l15;
        #pragma unroll
        for (int ks = 0; ks < 2; ++ks) {
            const int a0 = ks * 32 + kg * 8;
            qfh[ks] = *(const half8*)(pQh + arow * 64 + a0);
            qfl[ks] = *(const half8*)(pQl + arow * 64 + a0);
        }
    };
    // S = Q K^T (3-term split-f16 MFMA); Q from regs, K from stable LDS
    auto computeS = [&](float4a* sacc) {
        #pragma unroll
        for (int mt = 0; mt < 8; ++mt) sacc[mt] = (float4a)0.0f;
        #pragma unroll
        for (int ks = 0; ks < 2; ++ks) {
            const int a0 = ks * 32 + kg * 8;
            const half8 ah = qfh[ks];
            const half8 al = qfl[ks];
            #pragma unroll
            for (int mt = 0; mt < 8; ++mt) {
                const int mcol = mq * 128 + mt * 16 + l15;
                const half8 bh = *(const half8*)(smem + OFF_KH + swz128(mcol, a0));
                const half8 bl = *(const half8*)(smem + OFF_KL + swz128(mcol, a0));
                sacc[mt] = __builtin_amdgcn_mfma_f32_16x16x32_f16(ah, bh, sacc[mt], 0, 0, 0);
                sacc[mt] = __builtin_amdgcn_mfma_f32_16x16x32_f16(ah, bl, sacc[mt], 0, 0, 0);
                sacc[mt] = __builtin_amdgcn_mfma_f32_16x16x32_f16(al, bh, sacc[mt], 0, 0, 0);
            }
        }
    };

    // ---- prologue: Q(0) fragments + S(0) ----
    loadQ(0);
    float4a sacc[8];
    computeS(sacc);

    // ============ Phase B: 4 chunks; S(ci+1) overlapped with fc(ci);
    //              3 barriers per chunk; yv issued at chunk top ============
    #pragma unroll 1
    for (int ci = 0; ci < 4; ++ci) {
        // ---- 0. residual-Y loads issued FIRST (fly across the whole chunk) ----
        float yv[8][4];
        #pragma unroll
        for (int i = 0; i < 8; ++i)
            #pragma unroll
            for (int jj = 0; jj < 4; ++jj) {
                const int row = ci * 64 + rt_s * 16 + kg * 4 + jj;
                const int col = cgf * 128 + i * 16 + l15;
                yv[i][jj] = Yb[(size_t)row * 16384 + col];
            }

        // ---- 1. softmax partials on sacc + red write ----
        float mloc[4];
        #pragma unroll
        for (int jj = 0; jj < 4; ++jj) {
            float m0 = sacc[0][jj];
            #pragma unroll
            for (int mt = 1; mt < 8; ++mt) m0 = fmaxf(m0, sacc[mt][jj]);
            m0 = fmaxf(m0, __shfl_xor(m0, 1));
            m0 = fmaxf(m0, __shfl_xor(m0, 2));
            m0 = fmaxf(m0, __shfl_xor(m0, 4));
            m0 = fmaxf(m0, __shfl_xor(m0, 8));
            mloc[jj] = m0;
        }
        #pragma unroll
        for (int mt = 0; mt < 8; ++mt)
            #pragma unroll
            for (int jj = 0; jj < 4; ++jj)
                sacc[mt][jj] = __expf(sacc[mt][jj] - mloc[jj]);
        #pragma unroll
        for (int jj = 0; jj < 4; ++jj) {
            float s0 = 0.0f;
            #pragma unroll
            for (int mt = 0; mt < 8; ++mt) s0 += sacc[mt][jj];
            s0 += __shfl_xor(s0, 1);
            s0 += __shfl_xor(s0, 2);
            s0 += __shfl_xor(s0, 4);
            s0 += __shfl_xor(s0, 8);
            if (l15 == 0) {
                const int rloc = rt_s * 16 + kg * 4 + jj;
                red1[rloc * 2 + mq] = mloc[jj];
                red2[rloc * 2 + mq] = s0;
            }
        }
        lds_barrier();                                       // barB

        // ---- 2. normalize + PT write; Q(ci+1) prefetch ----
        #pragma unroll
        for (int jj = 0; jj < 4; ++jj) {
            const int rloc = rt_s * 16 + kg * 4 + jj;
            const float rm0 = red1[rloc * 2], rm1 = red1[rloc * 2 + 1];
            const float rs0 = red2[rloc * 2], rs1 = red2[rloc * 2 + 1];
            const float gmax = fmaxf(rm0, rm1);
            const float total = rs0 * __expf(rm0 - gmax) + rs1 * __expf(rm1 - gmax);
            const float fac = __expf(mloc[jj] - gmax) / total;
            #pragma unroll
            for (int mt = 0; mt < 8; ++mt) {
                const int mcol = mq * 128 + mt * 16 + l15;
                *(_Float16*)(smem + OFF_PT + swz512(rloc, mcol)) =
                    (_Float16)(sacc[mt][jj] * fac);
            }
        }
        if (ci < 3) loadQ(ci + 1);   // in flight across barC/barD (no vmcnt drain)
        lds_barrier();                                       // barC

        // ---- 3. PV = P * V -> PVH (single f16) ----
        float4a pacc[2];
        pacc[0] = (float4a)0.0f; pacc[1] = (float4a)0.0f;
        __builtin_amdgcn_s_setprio(1);
        #pragma unroll
        for (int ks = 0; ks < 8; ++ks) {
            const int mk = ks * 32 + kg * 8;
            const half8 pa = *(const half8*)(smem + OFF_PT + swz512(rt_s * 16 + l15, mk));
            #pragma unroll
            for (int i = 0; i < 2; ++i) {
                const half8 vb = *(const half8*)(smem + OFF_VST + swz512((ah2 * 2 + i) * 16 + l15, mk));
                pacc[i] = __builtin_amdgcn_mfma_f32_16x16x32_f16(pa, vb, pacc[i], 0, 0, 0);
            }
        }
        __builtin_amdgcn_s_setprio(0);
        #pragma unroll
        for (int i = 0; i < 2; ++i)
            #pragma unroll
            for (int jj = 0; jj < 4; ++jj) {
                const int rloc = rt_s * 16 + kg * 4 + jj;
                const int colp = (ah2 * 2 + i) * 16 + l15;
                *(_Float16*)(smem + OFF_PVH + swz128(rloc, colp)) =
                    (_Float16)pacc[i][jj];
            }
        lds_barrier();                                       // barD

        // ---- 4. fc(ci) single-term MFMA + S(ci+1) MFMA + store ----
        __builtin_amdgcn_s_setprio(1);
        if (ci < 3) computeS(sacc);   // reads stable KH/KL + prefetched Q regs
        float4a facc[8];
        #pragma unroll
        for (int i = 0; i < 8; ++i) facc[i] = (float4a)0.0f;
        #pragma unroll
        for (int ks = 0; ks < 2; ++ks) {
            const int aoff = ks * 32 + kg * 8;
            const half8 ah = *(const half8*)(smem + OFF_PVH + swz128(rt_s * 16 + l15, aoff));
            #pragma unroll
            for (int i = 0; i < 8; ++i) {
                const int cc = cgf * 128 + i * 16 + l15;
                const half8 bfh = *(const half8*)(ws + WS_FC + cc * 64 + aoff);
                facc[i] = __builtin_amdgcn_mfma_f32_16x16x32_f16(ah, bfh, facc[i], 0, 0, 0);
            }
        }
        __builtin_amdgcn_s_setprio(0);
        #pragma unroll
        for (int i = 0; i < 8; ++i)
            #pragma unroll
            for (int jj = 0; jj < 4; ++jj) {
                const int row = ci * 64 + rt_s * 16 + kg * 4 + jj;
                const int col = cgf * 128 + i * 16 + l15;
                Ob[(size_t)row * 16384 + col] =
                    yv[i][jj] + gv * (facc[i][jj] + fcbv[i]);
            }
        // no trailing barrier: cross-chunk LDS pairs separated by barB/barC.
    }
}

extern "C" void kernel_launch(void* const* d_in, const int* in_sizes, int n_in,
                              void* d_out, int out_size, void* d_ws, size_t ws_size,
                              hipStream_t stream) {
    (void)in_sizes; (void)n_in; (void)ws_size; (void)out_size;
    const float* Y    = (const float*)d_in[0];
    const float* Wq   = (const float*)d_in[1];
    const float* Wk   = (const float*)d_in[2];
    const float* Wv   = (const float*)d_in[3];
    const float* bq   = (const float*)d_in[4];
    const float* bk   = (const float*)d_in[5];
    const float* bv   = (const float*)d_in[6];
    const float* gama = (const float*)d_in[7];
    const float* fcw  = (const float*)d_in[8];
    const float* fcb  = (const float*)d_in[9];
    float* outp = (float*)d_out;
    _Float16* ws = (_Float16*)d_ws;

    (void)hipFuncSetAttribute((const void*)va_fused,
                              hipFuncAttributeMaxDynamicSharedMemorySize, LDS_BYTES);

    va_prep<<<dim3(193), dim3(256), 0, stream>>>(Wq, Wk, Wv, fcw, ws);
    va_fused<<<dim3(1024), dim3(512), LDS_BYTES, stream>>>(
        Y, bq, bk, bv, gama, fcb, ws, outp);
}

// Round 22
// 297.474 us; speedup vs baseline: 1.2225x; 1.2225x over previous
//
#include <hip/hip_runtime.h>
#include <hip/hip_fp16.h>

typedef __attribute__((ext_vector_type(8))) _Float16 half8;
typedef __attribute__((ext_vector_type(4))) _Float16 half4;
typedef __attribute__((ext_vector_type(4))) float float4a;

// ---- workspace layout (elements of _Float16) ----
#define WT_PLANE 3145728
#define WS_FC    6291456
#define WS_FC_LO 6307840
#define WS_Q     6324224          // per-block Q planes: [bl][Qh 16384 | Ql 16384]
#define Q_STRIDE 32768

// ---- LDS layout (bytes), total 163840 ----
#define OFF_KH   0
#define OFF_KL   32768
#define OFF_VST  65536
#define OFF_XB1  98304
#define OFF_PT   114688
#define OFF_PVH  147456
#define OFF_RED1 98304    // dead X region during phase B (no PVH alias)
#define OFF_RED2 99328
#define LDS_BYTES 163840

__device__ __forceinline__ int swz128(int r, int c) {
    return (r << 7) + ((((c >> 3) ^ r) & 7) << 4) + ((c & 7) << 1);
}
__device__ __forceinline__ int swz512(int r, int c) {
    return (r << 9) + (((((c >> 3) ^ (r & 7))) & 31) << 4) + ((c & 7) << 1);
}

// LDS-only barrier: does NOT drain vmcnt (global loads/stores stay in flight).
__device__ __forceinline__ void lds_barrier() {
    __builtin_amdgcn_sched_barrier(0);
    asm volatile("s_waitcnt lgkmcnt(0)" ::: "memory");
    __builtin_amdgcn_s_barrier();
    __builtin_amdgcn_sched_barrier(0);
}

// ---------------- prep: W -> WT (f16 hi/lo, transposed), fcw -> f16 hi/lo ----
extern "C" __global__ void __launch_bounds__(256)
va_prep(const float* __restrict__ Wq, const float* __restrict__ Wk,
        const float* __restrict__ Wv, const float* __restrict__ fcw,
        _Float16* __restrict__ ws)
{
    __shared__ float tile[16384];
    const int t = (int)threadIdx.x;
    const int blk = (int)blockIdx.x;
    if (blk < 192) {
        const int mat = blk >> 6, l = blk & 63;
        const float* W = (mat == 0 ? Wq : mat == 1 ? Wk : Wv) + l * 16384;
        #pragma unroll
        for (int i = 0; i < 16; ++i) {
            const int f = (i * 256 + t) * 4;
            *(float4a*)&tile[f] = *(const float4a*)(W + f);
        }
        __syncthreads();
        const int a = t & 63, cgp = t >> 6;
        const int obase = ((mat * 64 + l) * 64 + a) * 256;
        #pragma unroll
        for (int p = 0; p < 8; ++p) {
            const int c0 = cgp * 64 + p * 8;
            half8 hh, hl;
            #pragma unroll
            for (int q = 0; q < 8; ++q) {
                const float v = tile[(c0 + q) * 64 + a];
                const _Float16 h = (_Float16)v;
                hh[q] = h;
                hl[q] = (_Float16)(v - (float)h);
            }
            *(half8*)(ws + obase + c0) = hh;
            *(half8*)(ws + WT_PLANE + obase + c0) = hl;
        }
    } else {
        #pragma unroll
        for (int i = 0; i < 16; ++i) {
            const int f = (i * 256 + t) * 4;
            const float4a v = *(const float4a*)(fcw + f);
            half4 hh, hl;
            #pragma unroll
            for (int q = 0; q < 4; ++q) {
                const _Float16 h = (_Float16)v[q];
                hh[q] = h;
                hl[q] = (_Float16)(v[q] - (float)h);
            }
            *(half4*)(ws + WS_FC + f) = hh;
            *(half4*)(ws + WS_FC_LO + f) = hl;
        }
    }
}

// ---------------- main fused kernel ----------------
// r22 == r20 (best: 298us, absmax 0.25). r21's setprio regressed (-22%):
// the intrinsics acted as scheduler fences, extended live ranges, spilled
// (WRITE 354->446MB). Final operating point of this structure:
//  - 512 thr / 2 waves/EU is the only spill-free shape (r3-r7, r11 falsify
//    1024-thr; r9/r12/r15/r17/r21 falsify any live-set growth).
//  - f16 hi/lo exact-fp32 emulation throughout the precision-critical path
//    (Q/K 3-term S); single-term V/PV/fc (error << 1.035 threshold).
//  - phase-B pipeline: S(ci+1) in fc(ci) slot; 3 LDS-only barriers/chunk;
//    yv at chunk top; Q via ws plane; direct C-layout store.
extern "C" __global__ void
__launch_bounds__(512)
__attribute__((amdgpu_waves_per_eu(2, 2)))
va_fused(const float* __restrict__ Y,
         const float* __restrict__ bq, const float* __restrict__ bk,
         const float* __restrict__ bv,
         const float* __restrict__ gama, const float* __restrict__ fcb,
         _Float16* __restrict__ ws,
         float* __restrict__ out)
{
    extern __shared__ char smem[];
    const int tid  = (int)threadIdx.x;
    const int w    = tid >> 6;    // wave 0..7
    const int lane = tid & 63;
    const int l15  = lane & 15;
    const int kg   = lane >> 4;

    // XCD-aware swizzle (bijective): each XCD sees a stable set of 8 l's.
    const int i0 = (int)blockIdx.x;
    const int x  = i0 & 7, q0 = i0 >> 3;
    const int b  = q0 >> 3;
    const int l  = ((q0 & 7) << 3) | x;

    const size_t base = (size_t)b * (256u * 16384u) + (size_t)l * 256u;
    const float* __restrict__ Yb = Y + base;
    float* __restrict__ Ob = out + base;
    const size_t qslot = (size_t)WS_Q + (size_t)((b << 6) | l) * Q_STRIDE;

    const int rg = w >> 2;   // phase A: row-group (rows rg*128..+127)
    const int cg = w & 3;    // phase A: a-subgroup

    // ============ Phase A: QKV = X * W (dbuf X, split-f16 MFMA) ============
    float4a acc[8][3];
    #pragma unroll
    for (int rt = 0; rt < 8; ++rt)
        #pragma unroll
        for (int ct = 0; ct < 3; ++ct) acc[rt][ct] = (float4a)0.0f;

    const int srow = tid >> 1;          // 0..255
    const int scol = (tid & 1) * 32;
    const float* xsrc = Yb + (size_t)srow * 16384 + scol;

    auto xstage = [&](const float4a* xr, int bufbase) {
        #pragma unroll
        for (int p = 0; p < 8; ++p) {
            const int c = scol + p * 4;
            half4 hh, hl;
            #pragma unroll
            for (int q = 0; q < 4; ++q) {
                const float v = xr[p][q];
                const _Float16 h = (_Float16)v;
                hh[q] = h;
                hl[q] = (_Float16)(v - (float)h);
            }
            *(half4*)(smem + bufbase + swz128(srow, c)) = hh;
            *(half4*)(smem + bufbase + 32768 + swz128(srow, c)) = hl;
        }
    };
    auto wload = [&](int kt, int ks, half8* bh, half8* bl) {
        #pragma unroll
        for (int ct = 0; ct < 3; ++ct) {
            const int widx = ((ct * 64 + l) * 64 + cg * 16 + l15) * 256
                             + kt * 64 + ks * 32 + kg * 8;
            bh[ct] = *(const half8*)(ws + widx);
            if (ct < 2) bl[ct] = *(const half8*)(ws + WT_PLANE + widx);
        }
    };
    auto acompute = [&](int bufbase, int coff, const half8* bh, const half8* bl) {
        #pragma unroll
        for (int rt = 0; rt < 8; ++rt) {
            const int row = rg * 128 + rt * 16 + l15;
            const half8 ah = *(const half8*)(smem + bufbase + swz128(row, coff + kg * 8));
            const half8 al = *(const half8*)(smem + bufbase + 32768 + swz128(row, coff + kg * 8));
            #pragma unroll
            for (int ct = 0; ct < 2; ++ct) {
                acc[rt][ct] = __builtin_amdgcn_mfma_f32_16x16x32_f16(ah, bh[ct], acc[rt][ct], 0, 0, 0);
                acc[rt][ct] = __builtin_amdgcn_mfma_f32_16x16x32_f16(ah, bl[ct], acc[rt][ct], 0, 0, 0);
                acc[rt][ct] = __builtin_amdgcn_mfma_f32_16x16x32_f16(al, bh[ct], acc[rt][ct], 0, 0, 0);
            }
            // V: single term (Xh*Wvh). Dropped Xl*Wvh ~= 8e-3 abs, at V's own
            // f16 storage-rounding scale; downstream tolerance ~0.1.
            acc[rt][2] = __builtin_amdgcn_mfma_f32_16x16x32_f16(ah, bh[2], acc[rt][2], 0, 0, 0);
        }
    };

    {
        float4a xr[8];
        #pragma unroll
        for (int p = 0; p < 8; ++p) xr[p] = *(const float4a*)(xsrc + p * 4);
        xstage(xr, 0);
        lds_barrier();
        #pragma unroll
        for (int p = 0; p < 8; ++p) xr[p] = *(const float4a*)(xsrc + 64 + p * 4);

        #pragma unroll 2
        for (int kt = 0; kt < 4; ++kt) {
            const int cur = (kt & 1) ? OFF_XB1 : 0;
            const int nxt = (kt & 1) ? 0 : OFF_XB1;
            if (kt < 3) xstage(xr, nxt);
            half8 bh0[3], bl0[2];
            wload(kt, 0, bh0, bl0);
            acompute(cur, 0, bh0, bl0);
            if (kt < 2) {
                #pragma unroll
                for (int p = 0; p < 8; ++p)
                    xr[p] = *(const float4a*)(xsrc + (kt + 2) * 64 + p * 4);
            }
            half8 bh1[3], bl1[2];
            wload(kt, 1, bh1, bl1);
            acompute(cur, 32, bh1, bl1);
            lds_barrier();
        }
    }

    // ---- epilogue: bias; K hi/lo + V^T -> LDS; Q -> linear staging @buf1 ----
    {
        const int a = cg * 16 + l15;
        const float biq = bq[a], bik = bk[a], biv = bv[a];
        #pragma unroll
        for (int rt = 0; rt < 8; ++rt) {
            #pragma unroll
            for (int jj = 0; jj < 4; ++jj) {
                const int m = rg * 128 + rt * 16 + kg * 4 + jj;
                const float qv = acc[rt][0][jj] + biq;
                const _Float16 qh_ = (_Float16)qv;
                *(_Float16*)(smem + OFF_XB1 + m * 128 + a * 2) = qh_;
                *(_Float16*)(smem + OFF_XB1 + 32768 + m * 128 + a * 2) =
                    (_Float16)(qv - (float)qh_);
                const float kv = acc[rt][1][jj] + bik;
                const _Float16 kh = (_Float16)kv;
                *(_Float16*)(smem + OFF_KH + swz128(m, a)) = kh;
                *(_Float16*)(smem + OFF_KL + swz128(m, a)) = (_Float16)(kv - (float)kh);
            }
            const int m0 = rg * 128 + rt * 16 + kg * 4;
            half4 vh;
            #pragma unroll
            for (int jj = 0; jj < 4; ++jj)
                vh[jj] = (_Float16)(acc[rt][2][jj] + biv);
            *(half4*)(smem + OFF_VST + swz512(a, m0)) = vh;
        }
    }
    lds_barrier();
    // coalesced Q export: LDS -> ws plane (half8 stores)
    {
        _Float16* pQhw = ws + qslot;
        _Float16* pQlw = pQhw + 16384;
        #pragma unroll
        for (int p = 0; p < 4; ++p) {
            const int e = tid * 32 + p * 8;
            *(half8*)(pQhw + e) = *(const half8*)(smem + OFF_XB1 + e * 2);
            *(half8*)(pQlw + e) = *(const half8*)(smem + OFF_XB1 + 32768 + e * 2);
        }
    }
    __syncthreads();   // full drain: Q stores visible (L2) to all waves' loads

    // ---- phase B constants ----
    const int rt_s = w & 3;    // chunk-local row-tile
    const int mq   = w >> 2;   // S: m-half
    const int ah2  = w >> 2;   // PV: a-half
    const int cgf  = w >> 2;   // fc: col-half (cc cgf*128..+127)
    const float gv = gama[0];
    float fcbv[8];
    #pragma unroll
    for (int i = 0; i < 8; ++i) fcbv[i] = fcb[cgf * 128 + i * 16 + l15];
    float* red1 = (float*)(smem + OFF_RED1);
    float* red2 = (float*)(smem + OFF_RED2);
    const _Float16* __restrict__ pQh = ws + qslot;
    const _Float16* __restrict__ pQl = pQh + 16384;

    half8 qfh[2], qfl[2];      // prefetched Q fragments for the chunk in flight
    auto loadQ = [&](int ci) {
        const int arow = ci * 64 + rt_s * 16 + l15;
        #pragma unroll
        for (int ks = 0; ks < 2; ++ks) {
            const int a0 = ks * 32 + kg * 8;
            qfh[ks] = *(const half8*)(pQh + arow * 64 + a0);
            qfl[ks] = *(const half8*)(pQl + arow * 64 + a0);
        }
    };
    // S = Q K^T (3-term split-f16 MFMA); Q from regs, K from stable LDS
    auto computeS = [&](float4a* sacc) {
        #pragma unroll
        for (int mt = 0; mt < 8; ++mt) sacc[mt] = (float4a)0.0f;
        #pragma unroll
        for (int ks = 0; ks < 2; ++ks) {
            const int a0 = ks * 32 + kg * 8;
            const half8 ah = qfh[ks];
            const half8 al = qfl[ks];
            #pragma unroll
            for (int mt = 0; mt < 8; ++mt) {
                const int mcol = mq * 128 + mt * 16 + l15;
                const half8 bh = *(const half8*)(smem + OFF_KH + swz128(mcol, a0));
                const half8 bl = *(const half8*)(smem + OFF_KL + swz128(mcol, a0));
                sacc[mt] = __builtin_amdgcn_mfma_f32_16x16x32_f16(ah, bh, sacc[mt], 0, 0, 0);
                sacc[mt] = __builtin_amdgcn_mfma_f32_16x16x32_f16(ah, bl, sacc[mt], 0, 0, 0);
                sacc[mt] = __builtin_amdgcn_mfma_f32_16x16x32_f16(al, bh, sacc[mt], 0, 0, 0);
            }
        }
    };

    // ---- prologue: Q(0) fragments + S(0) ----
    loadQ(0);
    float4a sacc[8];
    computeS(sacc);

    // ============ Phase B: 4 chunks; S(ci+1) overlapped with fc(ci);
    //              3 barriers per chunk; yv issued at chunk top ============
    #pragma unroll 1
    for (int ci = 0; ci < 4; ++ci) {
        // ---- 0. residual-Y loads issued FIRST (fly across the whole chunk) ----
        float yv[8][4];
        #pragma unroll
        for (int i = 0; i < 8; ++i)
            #pragma unroll
            for (int jj = 0; jj < 4; ++jj) {
                const int row = ci * 64 + rt_s * 16 + kg * 4 + jj;
                const int col = cgf * 128 + i * 16 + l15;
                yv[i][jj] = Yb[(size_t)row * 16384 + col];
            }

        // ---- 1. softmax partials on sacc + red write ----
        float mloc[4];
        #pragma unroll
        for (int jj = 0; jj < 4; ++jj) {
            float m0 = sacc[0][jj];
            #pragma unroll
            for (int mt = 1; mt < 8; ++mt) m0 = fmaxf(m0, sacc[mt][jj]);
            m0 = fmaxf(m0, __shfl_xor(m0, 1));
            m0 = fmaxf(m0, __shfl_xor(m0, 2));
            m0 = fmaxf(m0, __shfl_xor(m0, 4));
            m0 = fmaxf(m0, __shfl_xor(m0, 8));
            mloc[jj] = m0;
        }
        #pragma unroll
        for (int mt = 0; mt < 8; ++mt)
            #pragma unroll
            for (int jj = 0; jj < 4; ++jj)
                sacc[mt][jj] = __expf(sacc[mt][jj] - mloc[jj]);
        #pragma unroll
        for (int jj = 0; jj < 4; ++jj) {
            float s0 = 0.0f;
            #pragma unroll
            for (int mt = 0; mt < 8; ++mt) s0 += sacc[mt][jj];
            s0 += __shfl_xor(s0, 1);
            s0 += __shfl_xor(s0, 2);
            s0 += __shfl_xor(s0, 4);
            s0 += __shfl_xor(s0, 8);
            if (l15 == 0) {
                const int rloc = rt_s * 16 + kg * 4 + jj;
                red1[rloc * 2 + mq] = mloc[jj];
                red2[rloc * 2 + mq] = s0;
            }
        }
        lds_barrier();                                       // barB

        // ---- 2. normalize + PT write; Q(ci+1) prefetch ----
        #pragma unroll
        for (int jj = 0; jj < 4; ++jj) {
            const int rloc = rt_s * 16 + kg * 4 + jj;
            const float rm0 = red1[rloc * 2], rm1 = red1[rloc * 2 + 1];
            const float rs0 = red2[rloc * 2], rs1 = red2[rloc * 2 + 1];
            const float gmax = fmaxf(rm0, rm1);
            const float total = rs0 * __expf(rm0 - gmax) + rs1 * __expf(rm1 - gmax);
            const float fac = __expf(mloc[jj] - gmax) / total;
            #pragma unroll
            for (int mt = 0; mt < 8; ++mt) {
                const int mcol = mq * 128 + mt * 16 + l15;
                *(_Float16*)(smem + OFF_PT + swz512(rloc, mcol)) =
                    (_Float16)(sacc[mt][jj] * fac);
            }
        }
        if (ci < 3) loadQ(ci + 1);   // in flight across barC/barD (no vmcnt drain)
        lds_barrier();                                       // barC

        // ---- 3. PV = P * V -> PVH (single f16) ----
        float4a pacc[2];
        pacc[0] = (float4a)0.0f; pacc[1] = (float4a)0.0f;
        #pragma unroll
        for (int ks = 0; ks < 8; ++ks) {
            const int mk = ks * 32 + kg * 8;
            const half8 pa = *(const half8*)(smem + OFF_PT + swz512(rt_s * 16 + l15, mk));
            #pragma unroll
            for (int i = 0; i < 2; ++i) {
                const half8 vb = *(const half8*)(smem + OFF_VST + swz512((ah2 * 2 + i) * 16 + l15, mk));
                pacc[i] = __builtin_amdgcn_mfma_f32_16x16x32_f16(pa, vb, pacc[i], 0, 0, 0);
            }
        }
        #pragma unroll
        for (int i = 0; i < 2; ++i)
            #pragma unroll
            for (int jj = 0; jj < 4; ++jj) {
                const int rloc = rt_s * 16 + kg * 4 + jj;
                const int colp = (ah2 * 2 + i) * 16 + l15;
                *(_Float16*)(smem + OFF_PVH + swz128(rloc, colp)) =
                    (_Float16)pacc[i][jj];
            }
        lds_barrier();                                       // barD

        // ---- 4. fc(ci) single-term MFMA + S(ci+1) MFMA + store ----
        if (ci < 3) computeS(sacc);   // reads stable KH/KL + prefetched Q regs
        float4a facc[8];
        #pragma unroll
        for (int i = 0; i < 8; ++i) facc[i] = (float4a)0.0f;
        #pragma unroll
        for (int ks = 0; ks < 2; ++ks) {
            const int aoff = ks * 32 + kg * 8;
            const half8 ah = *(const half8*)(smem + OFF_PVH + swz128(rt_s * 16 + l15, aoff));
            #pragma unroll
            for (int i = 0; i < 8; ++i) {
                const int cc = cgf * 128 + i * 16 + l15;
                const half8 bfh = *(const half8*)(ws + WS_FC + cc * 64 + aoff);
                facc[i] = __builtin_amdgcn_mfma_f32_16x16x32_f16(ah, bfh, facc[i], 0, 0, 0);
            }
        }
        #pragma unroll
        for (int i = 0; i < 8; ++i)
            #pragma unroll
            for (int jj = 0; jj < 4; ++jj) {
                const int row = ci * 64 + rt_s * 16 + kg * 4 + jj;
                const int col = cgf * 128 + i * 16 + l15;
                Ob[(size_t)row * 16384 + col] =
                    yv[i][jj] + gv * (facc[i][jj] + fcbv[i]);
            }
        // no trailing barrier: cross-chunk LDS pairs separated by barB/barC.
    }
}

extern "C" void kernel_launch(void* const* d_in, const int* in_sizes, int n_in,
                              void* d_out, int out_size, void* d_ws, size_t ws_size,
                              hipStream_t stream) {
    (void)in_sizes; (void)n_in; (void)ws_size; (void)out_size;
    const float* Y    = (const float*)d_in[0];
    const float* Wq   = (const float*)d_in[1];
    const float* Wk   = (const float*)d_in[2];
    const float* Wv   = (const float*)d_in[3];
    const float* bq   = (const float*)d_in[4];
    const float* bk   = (const float*)d_in[5];
    const float* bv   = (const float*)d_in[6];
    const float* gama = (const float*)d_in[7];
    const float* fcw  = (const float*)d_in[8];
    const float* fcb  = (const float*)d_in[9];
    float* outp = (float*)d_out;
    _Float16* ws = (_Float16*)d_ws;

    (void)hipFuncSetAttribute((const void*)va_fused,
                              hipFuncAttributeMaxDynamicSharedMemorySize, LDS_BYTES);

    va_prep<<<dim3(193), dim3(256), 0, stream>>>(Wq, Wk, Wv, fcw, ws);
    va_fused<<<dim3(1024), dim3(512), LDS_BYTES, stream>>>(
        Y, bq, bk, bv, gama, fcb, ws, outp);
}